// Round 1
// baseline (920.108 us; speedup 1.0000x reference)
//
#include <hip/hip_runtime.h>
#include <hip/hip_bf16.h>

// AttentionBlock: B=4, C=128, N=4096, GROUPS=8
// Pipeline: gn_stats -> gn_apply (h bf16) -> qkv_proj (q*scale,k,v bf16)
//           -> flash_attn (vector, online softmax) -> out_proj (+residual)

#define BATCH 4
#define CH 128
#define SEQ 4096
#define EPSV 1e-5f
#define QSCALE 0.08838834764831845f   // 1/sqrt(128)

typedef unsigned short u16;
typedef unsigned int u32;

__device__ __forceinline__ float bf2f(u16 h) {
    return __uint_as_float(((u32)h) << 16);
}
__device__ __forceinline__ u16 f2bf(float f) {
    u32 u = __float_as_uint(f);
    return (u16)((u + 0x7fffu + ((u >> 16) & 1u)) >> 16);
}

// ---------------- Kernel 1: GroupNorm statistics (one block per (b,g)) ---------
// Channels of group g are contiguous: segment of 16*4096 = 65536 floats.
__global__ void gn_stats(const float* __restrict__ x, float* __restrict__ stats) {
    int bg = blockIdx.x;  // 32
    const float4* xp = (const float4*)(x + (size_t)bg * 65536);
    float s = 0.f, sq = 0.f;
    for (int r = 0; r < 64; ++r) {
        float4 v = xp[threadIdx.x + 256 * r];
        s  += v.x + v.y + v.z + v.w;
        sq += v.x*v.x + v.y*v.y + v.z*v.z + v.w*v.w;
    }
    for (int off = 32; off; off >>= 1) {
        s  += __shfl_down(s, off, 64);
        sq += __shfl_down(sq, off, 64);
    }
    __shared__ float ls[8];
    int wave = threadIdx.x >> 6, lane = threadIdx.x & 63;
    if (lane == 0) { ls[wave*2] = s; ls[wave*2+1] = sq; }
    __syncthreads();
    if (threadIdx.x == 0) {
        float ts = 0.f, tq = 0.f;
        for (int w = 0; w < 4; ++w) { ts += ls[w*2]; tq += ls[w*2+1]; }
        float mean = ts / 65536.f;
        float var  = tq / 65536.f - mean * mean;
        stats[bg]      = mean;
        stats[32 + bg] = rsqrtf(var + EPSV);
    }
}

// ---------------- Kernel 2: apply GN, write h as bf16 --------------------------
__global__ void gn_apply(const float* __restrict__ x, const float* __restrict__ gw,
                         const float* __restrict__ gb, const float* __restrict__ stats,
                         u16* __restrict__ h) {
    int idx4 = blockIdx.x * 256 + threadIdx.x;  // 524288 float4 total
    int f = idx4 * 4;
    int b = f >> 19;            // C*N = 2^19
    int rem = f & 524287;
    int c = rem >> 12;          // N = 2^12
    int bg = b * 8 + (c >> 4);
    float mean = stats[bg], rstd = stats[32 + bg];
    float w = gw[c] * rstd;
    float bias = gb[c] - mean * w;
    float4 v = ((const float4*)x)[idx4];
    ushort4 o;
    o.x = f2bf(fmaf(v.x, w, bias));
    o.y = f2bf(fmaf(v.y, w, bias));
    o.z = f2bf(fmaf(v.z, w, bias));
    o.w = f2bf(fmaf(v.w, w, bias));
    ((ushort4*)h)[idx4] = o;
}

// ---------------- Kernel 3: QKV 1x1-conv projection ----------------------------
// block = (b, o, n-chunk of 256). q rows pre-scaled by 1/sqrt(C).
__global__ void qkv_proj(const u16* __restrict__ h, const float* __restrict__ w_qkv,
                         const float* __restrict__ b_qkv, u16* __restrict__ q,
                         u16* __restrict__ k, u16* __restrict__ v) {
    int bx = blockIdx.x;              // 4*384*16
    int nb = bx & 15;
    int o  = (bx >> 4) % 384;
    int b  = bx / (384 * 16);
    __shared__ float wrow[128];
    if (threadIdx.x < 128) wrow[threadIdx.x] = w_qkv[o * 128 + threadIdx.x];
    __syncthreads();
    int n = nb * 256 + threadIdx.x;
    const u16* hb = h + (size_t)b * CH * SEQ + n;
    float acc = 0.f;
    #pragma unroll 8
    for (int c = 0; c < 128; ++c)
        acc = fmaf(wrow[c], bf2f(hb[(size_t)c * SEQ]), acc);
    acc += b_qkv[o];
    if (o < 128) {
        q[(size_t)(b * 128 + o) * SEQ + n] = f2bf(acc * QSCALE);
    } else if (o < 256) {
        k[(size_t)(b * 128 + (o - 128)) * SEQ + n] = f2bf(acc);
    } else {
        v[(size_t)(b * 128 + (o - 256)) * SEQ + n] = f2bf(acc);
    }
}

// ---------------- Kernel 4: flash attention (vector baseline) ------------------
// Block handles (b, 32 i-rows). j swept in chunks of 128 with online softmax.
// Score mapping: thread = (ig 0..7, jl 0..31) -> 4i x 4j register tile.
// PV mapping:    thread = (cc 0..127, ih 0..1) -> 1c x 16i accumulators.
#define KSTRIDE 136   // padded LDS row (bf16 elems): 272B = 17 uint4, kills 32-way bank conflicts

__global__ __launch_bounds__(256, 2) void flash_attn(
        const u16* __restrict__ q, const u16* __restrict__ k,
        const u16* __restrict__ v, float* __restrict__ h2) {
    __shared__ u16  qs[128 * 32];           // q tile, [c][i], 8 KB
    __shared__ u16  kvs[128 * KSTRIDE];     // k then v tile, [c][j] padded, 34 KB
    __shared__ float ps[128 * 32];          // p, [j][i], 16 KB
    __shared__ float alphas[32];
    __shared__ float lsh[32];

    int b  = blockIdx.x >> 7;    // 4 * 128 blocks
    int it = blockIdx.x & 127;
    int i0 = it * 32;
    int t  = threadIdx.x;

    // load q tile: 128 rows x 32 bf16
    {
        const u16* qb = q + (size_t)b * CH * SEQ + i0;
        for (int r = 0; r < 2; ++r) {
            int u = t + 256 * r;
            int c = u >> 2, p4 = u & 3;
            uint4 val = *(const uint4*)(qb + (size_t)c * SEQ + p4 * 8);
            *(uint4*)(qs + c * 32 + p4 * 8) = val;
        }
    }

    int ig = t >> 5, jl = t & 31;   // score-phase mapping
    int cc = t >> 1, ih = t & 1;    // PV-phase mapping
    float m_run[4], l_run[4];
    #pragma unroll
    for (int ii = 0; ii < 4; ++ii) { m_run[ii] = -INFINITY; l_run[ii] = 0.f; }
    float acc[16];
    #pragma unroll
    for (int r = 0; r < 16; ++r) acc[r] = 0.f;

    const u16* kb = k + (size_t)b * CH * SEQ;
    const u16* vb = v + (size_t)b * CH * SEQ;

    for (int jc = 0; jc < SEQ; jc += 128) {
        __syncthreads();  // previous PV done: kvs/ps/alphas reusable
        // stage K tile [128c][128j]
        for (int r = 0; r < 8; ++r) {
            int u = t + 256 * r;
            int c = u >> 4, col = u & 15;
            uint4 val = *(const uint4*)(kb + (size_t)c * SEQ + jc + col * 8);
            *(uint4*)(kvs + c * KSTRIDE + col * 8) = val;
        }
        __syncthreads();
        // scores (q pre-scaled): 4i x 4j per thread
        float sv[16];
        #pragma unroll
        for (int r = 0; r < 16; ++r) sv[r] = 0.f;
        for (int c = 0; c < 128; ++c) {
            ushort4 qv = *(const ushort4*)(qs + c * 32 + ig * 4);
            ushort4 kv = *(const ushort4*)(kvs + c * KSTRIDE + jl * 4);
            float qf[4] = {bf2f(qv.x), bf2f(qv.y), bf2f(qv.z), bf2f(qv.w)};
            float kf[4] = {bf2f(kv.x), bf2f(kv.y), bf2f(kv.z), bf2f(kv.w)};
            #pragma unroll
            for (int ii = 0; ii < 4; ++ii)
                #pragma unroll
                for (int jj = 0; jj < 4; ++jj)
                    sv[ii*4+jj] = fmaf(qf[ii], kf[jj], sv[ii*4+jj]);
        }
        // online softmax per i-row (reduce over 32 jl lanes; masks<=16 stay in half-wave)
        #pragma unroll
        for (int ii = 0; ii < 4; ++ii) {
            float mx = fmaxf(fmaxf(sv[ii*4], sv[ii*4+1]), fmaxf(sv[ii*4+2], sv[ii*4+3]));
            for (int off = 16; off; off >>= 1)
                mx = fmaxf(mx, __shfl_xor(mx, off, 64));
            float mnew = fmaxf(m_run[ii], mx);
            float al = __expf(m_run[ii] - mnew);
            float lsum = 0.f;
            #pragma unroll
            for (int jj = 0; jj < 4; ++jj) {
                float p = __expf(sv[ii*4+jj] - mnew);
                sv[ii*4+jj] = p;
                lsum += p;
            }
            for (int off = 16; off; off >>= 1)
                lsum += __shfl_xor(lsum, off, 64);
            l_run[ii] = l_run[ii] * al + lsum;
            m_run[ii] = mnew;
            if (jl == 0) alphas[ig * 4 + ii] = al;
            #pragma unroll
            for (int jj = 0; jj < 4; ++jj)
                ps[(jl * 4 + jj) * 32 + ig * 4 + ii] = sv[ii*4+jj];
        }
        __syncthreads();  // ks consumed, ps/alphas published
        // stage V tile over kvs
        for (int r = 0; r < 8; ++r) {
            int u = t + 256 * r;
            int c = u >> 4, col = u & 15;
            uint4 val = *(const uint4*)(vb + (size_t)c * SEQ + jc + col * 8);
            *(uint4*)(kvs + c * KSTRIDE + col * 8) = val;
        }
        __syncthreads();
        // PV: acc[r] over i = ih*16 + r, single channel cc
        {
            #pragma unroll
            for (int r = 0; r < 16; ++r) acc[r] *= alphas[ih * 16 + r];
            const u16* vrow = kvs + cc * KSTRIDE;
            const float* pbase = ps + ih * 16;
            #pragma unroll 2
            for (int j = 0; j < 128; ++j) {
                float vf = bf2f(vrow[j]);
                const float4* pr = (const float4*)(pbase + j * 32);
                float4 p0 = pr[0], p1 = pr[1], p2 = pr[2], p3 = pr[3];
                acc[0]  = fmaf(vf, p0.x, acc[0]);  acc[1]  = fmaf(vf, p0.y, acc[1]);
                acc[2]  = fmaf(vf, p0.z, acc[2]);  acc[3]  = fmaf(vf, p0.w, acc[3]);
                acc[4]  = fmaf(vf, p1.x, acc[4]);  acc[5]  = fmaf(vf, p1.y, acc[5]);
                acc[6]  = fmaf(vf, p1.z, acc[6]);  acc[7]  = fmaf(vf, p1.w, acc[7]);
                acc[8]  = fmaf(vf, p2.x, acc[8]);  acc[9]  = fmaf(vf, p2.y, acc[9]);
                acc[10] = fmaf(vf, p2.z, acc[10]); acc[11] = fmaf(vf, p2.w, acc[11]);
                acc[12] = fmaf(vf, p3.x, acc[12]); acc[13] = fmaf(vf, p3.y, acc[13]);
                acc[14] = fmaf(vf, p3.z, acc[14]); acc[15] = fmaf(vf, p3.w, acc[15]);
            }
        }
    }
    __syncthreads();
    if (jl == 0) {
        #pragma unroll
        for (int ii = 0; ii < 4; ++ii) lsh[ig * 4 + ii] = l_run[ii];
    }
    __syncthreads();
    float* outp = h2 + ((size_t)(b * CH + cc) * SEQ + i0 + ih * 16);
    #pragma unroll
    for (int r = 0; r < 16; ++r) acc[r] /= lsh[ih * 16 + r];
    #pragma unroll
    for (int qq = 0; qq < 4; ++qq) {
        float4 o = make_float4(acc[qq*4], acc[qq*4+1], acc[qq*4+2], acc[qq*4+3]);
        *(float4*)(outp + qq * 4) = o;
    }
}

// ---------------- Kernel 5: out projection + bias + residual -------------------
__global__ void out_proj(const float* __restrict__ h2, const float* __restrict__ w_out,
                         const float* __restrict__ b_out, const float* __restrict__ x,
                         float* __restrict__ out) {
    int bx = blockIdx.x;          // 4*128*16
    int nb = bx & 15;
    int o  = (bx >> 4) & 127;
    int b  = bx >> 11;
    __shared__ float wrow[128];
    if (threadIdx.x < 128) wrow[threadIdx.x] = w_out[o * 128 + threadIdx.x];
    __syncthreads();
    int n = nb * 256 + threadIdx.x;
    const float* hb = h2 + (size_t)b * CH * SEQ + n;
    float acc = 0.f;
    #pragma unroll 8
    for (int c = 0; c < 128; ++c)
        acc = fmaf(wrow[c], hb[(size_t)c * SEQ], acc);
    size_t oidx = (size_t)(b * CH + o) * SEQ + n;
    out[oidx] = acc + b_out[o] + x[oidx];
}

// ---------------- launch -------------------------------------------------------
extern "C" void kernel_launch(void* const* d_in, const int* in_sizes, int n_in,
                              void* d_out, int out_size, void* d_ws, size_t ws_size,
                              hipStream_t stream) {
    const float* x     = (const float*)d_in[0];
    const float* gn_w  = (const float*)d_in[1];
    const float* gn_b  = (const float*)d_in[2];
    const float* w_qkv = (const float*)d_in[3];
    const float* b_qkv = (const float*)d_in[4];
    const float* w_out = (const float*)d_in[5];
    const float* b_out = (const float*)d_in[6];
    float* out = (float*)d_out;

    char* ws = (char*)d_ws;
    float* stats = (float*)ws;                       // 64 floats
    u16* h = (u16*)(ws + 4096);                      // 2M bf16 = 4 MB
    u16* q = h + 2097152;                            // 4 MB
    u16* k = q + 2097152;                            // 4 MB
    u16* v = k + 2097152;                            // 4 MB
    float* h2 = (float*)(ws + 4096 + (size_t)4 * 4194304);  // 8 MB
    // total ws use: ~25.2 MB

    gn_stats<<<32, 256, 0, stream>>>(x, stats);
    gn_apply<<<2048, 256, 0, stream>>>(x, gn_w, gn_b, stats, h);
    qkv_proj<<<4 * 384 * 16, 256, 0, stream>>>(h, w_qkv, b_qkv, q, k, v);
    flash_attn<<<4 * 128, 256, 0, stream>>>(q, k, v, h2);
    out_proj<<<4 * 128 * 16, 256, 0, stream>>>(h2, w_out, b_out, x, out);
}

// Round 2
// 313.954 us; speedup vs baseline: 2.9307x; 2.9307x over previous
//
#include <hip/hip_runtime.h>

// AttentionBlock B=4, C=128, N=4096.
// gn_stats -> gn_apply (h bf16) -> qkv_proj (q*scale*log2e, k, v bf16)
// -> ktrans (kT [n][c]) -> flash_attn (MFMA 16x16x32 bf16, 4-way j-split,
// online softmax base-2) -> merge_attn (combine partials -> h2 bf16)
// -> out_proj (+bias +residual, fp32 out)

#define CH 128
#define SEQ 4096
#define EPSV 1e-5f
// 1/sqrt(128) * log2(e): softmax runs in base-2 domain
#define QSCALE (0.08838834764831845f * 1.4426950408889634f)

typedef unsigned short u16;
typedef unsigned int u32;
typedef __attribute__((ext_vector_type(8))) short short8;   // 8 bf16 (4 VGPRs)
typedef __attribute__((ext_vector_type(4))) float floatx4;  // MFMA C/D

__device__ __forceinline__ float bf2f(u16 h) {
    return __uint_as_float(((u32)h) << 16);
}
__device__ __forceinline__ u16 f2bf(float f) {
    u32 u = __float_as_uint(f);
    return (u16)((u + 0x7fffu + ((u >> 16) & 1u)) >> 16);
}
__device__ __forceinline__ floatx4 mfma16(short8 a, short8 b, floatx4 c) {
    return __builtin_amdgcn_mfma_f32_16x16x32_bf16(a, b, c, 0, 0, 0);
}

// ---------------- Kernel 1: GroupNorm statistics -------------------------------
__global__ void gn_stats(const float* __restrict__ x, float* __restrict__ stats) {
    int bg = blockIdx.x;  // 32
    const float4* xp = (const float4*)(x + (size_t)bg * 65536);
    float s = 0.f, sq = 0.f;
    for (int r = 0; r < 64; ++r) {
        float4 v = xp[threadIdx.x + 256 * r];
        s  += v.x + v.y + v.z + v.w;
        sq += v.x*v.x + v.y*v.y + v.z*v.z + v.w*v.w;
    }
    for (int off = 32; off; off >>= 1) {
        s  += __shfl_down(s, off, 64);
        sq += __shfl_down(sq, off, 64);
    }
    __shared__ float ls[8];
    int wave = threadIdx.x >> 6, lane = threadIdx.x & 63;
    if (lane == 0) { ls[wave*2] = s; ls[wave*2+1] = sq; }
    __syncthreads();
    if (threadIdx.x == 0) {
        float ts = 0.f, tq = 0.f;
        for (int w = 0; w < 4; ++w) { ts += ls[w*2]; tq += ls[w*2+1]; }
        float mean = ts / 65536.f;
        float var  = tq / 65536.f - mean * mean;
        stats[bg]      = mean;
        stats[32 + bg] = rsqrtf(var + EPSV);
    }
}

// ---------------- Kernel 2: apply GN, h bf16 -----------------------------------
__global__ void gn_apply(const float* __restrict__ x, const float* __restrict__ gw,
                         const float* __restrict__ gb, const float* __restrict__ stats,
                         u16* __restrict__ h) {
    int idx4 = blockIdx.x * 256 + threadIdx.x;
    int f = idx4 * 4;
    int b = f >> 19;
    int rem = f & 524287;
    int c = rem >> 12;
    int bg = b * 8 + (c >> 4);
    float mean = stats[bg], rstd = stats[32 + bg];
    float w = gw[c] * rstd;
    float bias = gb[c] - mean * w;
    float4 v = ((const float4*)x)[idx4];
    ushort4 o;
    o.x = f2bf(fmaf(v.x, w, bias));
    o.y = f2bf(fmaf(v.y, w, bias));
    o.z = f2bf(fmaf(v.z, w, bias));
    o.w = f2bf(fmaf(v.w, w, bias));
    ((ushort4*)h)[idx4] = o;
}

// ---------------- Kernel 3: QKV projection -------------------------------------
__global__ void qkv_proj(const u16* __restrict__ h, const float* __restrict__ w_qkv,
                         const float* __restrict__ b_qkv, u16* __restrict__ q,
                         u16* __restrict__ k, u16* __restrict__ v) {
    int bx = blockIdx.x;              // 4*384*16
    int nb = bx & 15;
    int o  = (bx >> 4) % 384;
    int b  = bx / (384 * 16);
    __shared__ float wrow[128];
    if (threadIdx.x < 128) wrow[threadIdx.x] = w_qkv[o * 128 + threadIdx.x];
    __syncthreads();
    int n = nb * 256 + threadIdx.x;
    const u16* hb = h + (size_t)b * CH * SEQ + n;
    float acc = 0.f;
    #pragma unroll 8
    for (int c = 0; c < 128; ++c)
        acc = fmaf(wrow[c], bf2f(hb[(size_t)c * SEQ]), acc);
    acc += b_qkv[o];
    if (o < 128) {
        q[(size_t)(b * 128 + o) * SEQ + n] = f2bf(acc * QSCALE);
    } else if (o < 256) {
        k[(size_t)(b * 128 + (o - 128)) * SEQ + n] = f2bf(acc);
    } else {
        v[(size_t)(b * 128 + (o - 256)) * SEQ + n] = f2bf(acc);
    }
}

// ---------------- Kernel 3b: transpose k -> kT [n][c] --------------------------
__global__ void ktrans(const u16* __restrict__ k, u16* __restrict__ kT) {
    int bx = blockIdx.x;  // 4*64
    int nt = bx & 63, b = bx >> 6;
    __shared__ u16 kls[64 * 136];
    int t = threadIdx.x;
    const u16* kb = k + (size_t)b * CH * SEQ + nt * 64;
    for (int r = 0; r < 4; ++r) {
        int u = r * 256 + t;
        int c = u >> 3, col = u & 7;
        uint4 val = *(const uint4*)(kb + (size_t)c * SEQ + col * 8);
        u16 a[8]; *(uint4*)a = val;
        #pragma unroll
        for (int e = 0; e < 8; ++e) kls[(col * 8 + e) * 136 + c] = a[e];
    }
    __syncthreads();
    u16* kTb = kT + ((size_t)b * SEQ + nt * 64) * CH;
    for (int r = 0; r < 4; ++r) {
        int u = r * 256 + t;
        int n = u >> 4, c16 = u & 15;
        *(uint4*)(kTb + (size_t)n * CH + c16 * 8) = *(const uint4*)(kls + n * 136 + c16 * 8);
    }
}

// ---------------- Kernel 4: MFMA flash attention -------------------------------
// Block: (b, iblk of 128 i-rows, js of 4 j-splits). 4 waves x 32 i-rows each.
// j sweep: 16 chunks of BN=64 within this split's 1024 j.
// S = Q^T K via mfma(A=Q^T[i][c], B=kT[j][c]); online softmax (base-2);
// P -> LDS ps[i][j] (per-wave slab, no barrier); O^T = V P^T via
// mfma(A=V[c][j], B=ps[i][j]). Partial O/m/l to workspace; merged later.
__global__ __launch_bounds__(256, 2) void flash_attn(
        const u16* __restrict__ q, const u16* __restrict__ kT,
        const u16* __restrict__ v, u16* __restrict__ partO,
        float* __restrict__ mbuf, float* __restrict__ lbuf) {
    __shared__ __align__(16) char smem[54784];
    u16* kts = (u16*)smem;                 // [64 j][136 c]   17408 B
    u16* vts = (u16*)(smem + 17408);       // [128 c][72 j]   18432 B
    u16* ps  = (u16*)(smem + 35840);       // [128 i][72 j]   18432 B
    float* als = (float*)(smem + 54272);   // [128 i]           512 B
    u16* qts = (u16*)smem;                 // [128 i][136 c] (init only)

    int bx = blockIdx.x;                   // 512
    int js = bx & 3, iblk = (bx >> 2) & 31, b = bx >> 7;
    int t = threadIdx.x, w = t >> 6, lane = t & 63;
    int quad = lane >> 4, l15 = lane & 15;
    int i0 = iblk * 128, j0 = js * 1024;

    // ---- stage Q tile transposed, read A-frags into registers (once) ----
    {
        const u16* qb = q + (size_t)b * CH * SEQ + i0;
        for (int r = 0; r < 8; ++r) {
            int u = r * 256 + t;
            int c = u >> 4, i8 = (u & 15) * 8;
            uint4 val = *(const uint4*)(qb + (size_t)c * SEQ + i8);
            u16 a[8]; *(uint4*)a = val;
            #pragma unroll
            for (int e = 0; e < 8; ++e) qts[(i8 + e) * 136 + c] = a[e];
        }
    }
    __syncthreads();
    short8 qf[2][4];
    #pragma unroll
    for (int mt = 0; mt < 2; ++mt)
        #pragma unroll
        for (int kt = 0; kt < 4; ++kt)
            qf[mt][kt] = *(const short8*)(qts + (w * 32 + mt * 16 + l15) * 136 + kt * 32 + quad * 8);
    __syncthreads();

    float m_run[8], l_run[8];
    #pragma unroll
    for (int r = 0; r < 8; ++r) { m_run[r] = -INFINITY; l_run[r] = 0.f; }
    floatx4 o[8][2];
    #pragma unroll
    for (int mt = 0; mt < 8; ++mt) { o[mt][0] = (floatx4)0.f; o[mt][1] = (floatx4)0.f; }

    const u16* kTb = kT + ((size_t)b * SEQ + j0) * CH;
    const u16* vb  = v  + (size_t)b * CH * SEQ + j0;

    for (int ch = 0; ch < 16; ++ch) {
        int jb = ch * 64;
        __syncthreads();  // all waves done reading prev kts/vts
        for (int r = 0; r < 4; ++r) {
            int u = r * 256 + t;
            int j = u >> 4, c16 = u & 15;
            *(uint4*)(kts + j * 136 + c16 * 8) =
                *(const uint4*)(kTb + (size_t)(jb + j) * CH + c16 * 8);
        }
        for (int r = 0; r < 4; ++r) {
            int u = r * 256 + t;
            int c = u >> 3, col = u & 7;
            *(uint4*)(vts + c * 72 + col * 8) =
                *(const uint4*)(vb + (size_t)c * SEQ + jb + col * 8);
        }
        __syncthreads();

        // ---- scores: 2 Mtiles x 4 jtiles, K=128 over 4 MFMAs ----
        floatx4 s[2][4];
        #pragma unroll
        for (int mt = 0; mt < 2; ++mt)
            #pragma unroll
            for (int jt = 0; jt < 4; ++jt) s[mt][jt] = (floatx4)0.f;
        #pragma unroll
        for (int jt = 0; jt < 4; ++jt)
            #pragma unroll
            for (int kt = 0; kt < 4; ++kt) {
                short8 bf = *(const short8*)(kts + (jt * 16 + l15) * 136 + kt * 32 + quad * 8);
                s[0][jt] = mfma16(qf[0][kt], bf, s[0][jt]);
                s[1][jt] = mfma16(qf[1][kt], bf, s[1][jt]);
            }

        // ---- online softmax (base-2), P -> ps (own-wave slab) ----
        #pragma unroll
        for (int mt = 0; mt < 2; ++mt) {
            float al[4];
            #pragma unroll
            for (int r = 0; r < 4; ++r) {
                float mx = fmaxf(fmaxf(s[mt][0][r], s[mt][1][r]),
                                 fmaxf(s[mt][2][r], s[mt][3][r]));
                mx = fmaxf(mx, __shfl_xor(mx, 1, 64));
                mx = fmaxf(mx, __shfl_xor(mx, 2, 64));
                mx = fmaxf(mx, __shfl_xor(mx, 4, 64));
                mx = fmaxf(mx, __shfl_xor(mx, 8, 64));
                float mo = m_run[mt * 4 + r];
                float mn = fmaxf(mo, mx);
                al[r] = exp2f(mo - mn);
                m_run[mt * 4 + r] = mn;
                float p0 = exp2f(s[mt][0][r] - mn);
                float p1 = exp2f(s[mt][1][r] - mn);
                float p2 = exp2f(s[mt][2][r] - mn);
                float p3 = exp2f(s[mt][3][r] - mn);
                int row = w * 32 + mt * 16 + quad * 4 + r;
                ps[row * 72 +  0 + l15] = f2bf(p0);
                ps[row * 72 + 16 + l15] = f2bf(p1);
                ps[row * 72 + 32 + l15] = f2bf(p2);
                ps[row * 72 + 48 + l15] = f2bf(p3);
                float lsum = p0 + p1 + p2 + p3;
                lsum += __shfl_xor(lsum, 1, 64);
                lsum += __shfl_xor(lsum, 2, 64);
                lsum += __shfl_xor(lsum, 4, 64);
                lsum += __shfl_xor(lsum, 8, 64);
                l_run[mt * 4 + r] = l_run[mt * 4 + r] * al[r] + lsum;
            }
            if (l15 == 0) {
                #pragma unroll
                for (int r = 0; r < 4; ++r) als[w * 32 + mt * 16 + quad * 4 + r] = al[r];
            }
        }
        __builtin_amdgcn_wave_barrier();  // keep ps/als writes before reads

        // ---- PV: O^T[c][i] += V[c][j] * P^T[j][i] ----
        float a0 = als[w * 32 + l15];
        float a1 = als[w * 32 + 16 + l15];
        #pragma unroll
        for (int mt = 0; mt < 8; ++mt) { o[mt][0] *= a0; o[mt][1] *= a1; }
        #pragma unroll
        for (int kt = 0; kt < 2; ++kt) {
            short8 pf0 = *(const short8*)(ps + (w * 32 + l15) * 72 + kt * 32 + quad * 8);
            short8 pf1 = *(const short8*)(ps + (w * 32 + 16 + l15) * 72 + kt * 32 + quad * 8);
            #pragma unroll
            for (int mt = 0; mt < 8; ++mt) {
                short8 vf = *(const short8*)(vts + (mt * 16 + l15) * 72 + kt * 32 + quad * 8);
                o[mt][0] = mfma16(vf, pf0, o[mt][0]);
                o[mt][1] = mfma16(vf, pf1, o[mt][1]);
            }
        }
    }

    // ---- epilogue: partial O (bf16), m, l ----
    int bi = b * 32 + iblk;
    u16* pb = partO + ((size_t)(js * 128 + bi)) * 16384;
    #pragma unroll
    for (int mt = 0; mt < 8; ++mt)
        #pragma unroll
        for (int nt = 0; nt < 2; ++nt)
            #pragma unroll
            for (int r = 0; r < 4; ++r)
                pb[(mt * 16 + quad * 4 + r) * 128 + w * 32 + nt * 16 + l15] = f2bf(o[mt][nt][r]);
    if (l15 == 0) {
        float* mb = mbuf + ((size_t)(js * 128 + bi)) * 128;
        float* lb = lbuf + ((size_t)(js * 128 + bi)) * 128;
        #pragma unroll
        for (int mt = 0; mt < 2; ++mt)
            #pragma unroll
            for (int r = 0; r < 4; ++r) {
                int i = w * 32 + mt * 16 + quad * 4 + r;
                mb[i] = m_run[mt * 4 + r];
                lb[i] = l_run[mt * 4 + r];
            }
    }
}

// ---------------- Kernel 4b: merge 4 j-split partials -> h2 bf16 ---------------
__global__ void merge_attn(const u16* __restrict__ partO, const float* __restrict__ mbuf,
                           const float* __restrict__ lbuf, u16* __restrict__ h2) {
    int bx = blockIdx.x;  // 512 = (b, iblk, cq)
    int cq = bx & 3, iblk = (bx >> 2) & 31, b = bx >> 7;
    int bi = b * 32 + iblk;
    __shared__ float fac[4][128];
    int t = threadIdx.x;
    if (t < 128) {
        float mv[4], lv[4];
        #pragma unroll
        for (int s = 0; s < 4; ++s) {
            mv[s] = mbuf[((size_t)(s * 128 + bi)) * 128 + t];
            lv[s] = lbuf[((size_t)(s * 128 + bi)) * 128 + t];
        }
        float M = fmaxf(fmaxf(mv[0], mv[1]), fmaxf(mv[2], mv[3]));
        float w0 = exp2f(mv[0] - M), w1 = exp2f(mv[1] - M);
        float w2 = exp2f(mv[2] - M), w3 = exp2f(mv[3] - M);
        float inv = 1.f / (w0 * lv[0] + w1 * lv[1] + w2 * lv[2] + w3 * lv[3]);
        fac[0][t] = w0 * inv; fac[1][t] = w1 * inv;
        fac[2][t] = w2 * inv; fac[3][t] = w3 * inv;
    }
    __syncthreads();
    int c = cq * 32 + (t >> 3);
    int ii = (t & 7) * 16;
    float acc[16];
    #pragma unroll
    for (int e = 0; e < 16; ++e) acc[e] = 0.f;
    for (int s = 0; s < 4; ++s) {
        const u16* pb = partO + ((size_t)(s * 128 + bi)) * 16384 + c * 128 + ii;
        const float* fs = fac[s] + ii;
        #pragma unroll
        for (int e = 0; e < 16; ++e) acc[e] = fmaf(bf2f(pb[e]), fs[e], acc[e]);
    }
    u16* hb = h2 + ((size_t)(b * CH + c)) * SEQ + iblk * 128 + ii;
    #pragma unroll
    for (int e = 0; e < 16; ++e) hb[e] = f2bf(acc[e]);
}

// ---------------- Kernel 5: out projection + bias + residual -------------------
__global__ void out_proj(const u16* __restrict__ h2, const float* __restrict__ w_out,
                         const float* __restrict__ b_out, const float* __restrict__ x,
                         float* __restrict__ out) {
    int bx = blockIdx.x;          // 4*128*16
    int nb = bx & 15;
    int o  = (bx >> 4) & 127;
    int b  = bx >> 11;
    __shared__ float wrow[128];
    if (threadIdx.x < 128) wrow[threadIdx.x] = w_out[o * 128 + threadIdx.x];
    __syncthreads();
    int n = nb * 256 + threadIdx.x;
    const u16* hb = h2 + (size_t)b * CH * SEQ + n;
    float acc = 0.f;
    #pragma unroll 8
    for (int c = 0; c < 128; ++c)
        acc = fmaf(wrow[c], bf2f(hb[(size_t)c * SEQ]), acc);
    size_t oidx = (size_t)(b * CH + o) * SEQ + n;
    out[oidx] = acc + b_out[o] + x[oidx];
}

// ---------------- launch -------------------------------------------------------
extern "C" void kernel_launch(void* const* d_in, const int* in_sizes, int n_in,
                              void* d_out, int out_size, void* d_ws, size_t ws_size,
                              hipStream_t stream) {
    const float* x     = (const float*)d_in[0];
    const float* gn_w  = (const float*)d_in[1];
    const float* gn_b  = (const float*)d_in[2];
    const float* w_qkv = (const float*)d_in[3];
    const float* b_qkv = (const float*)d_in[4];
    const float* w_out = (const float*)d_in[5];
    const float* b_out = (const float*)d_in[6];
    float* out = (float*)d_out;

    char* ws = (char*)d_ws;
    float* stats = (float*)ws;                       //     4 KB @ 0
    u16*  h    = (u16*)(ws + 4096);                  //  4 MB
    u16*  q    = (u16*)(ws + 4198400);               //  4 MB
    u16*  k    = (u16*)(ws + 8392704);               //  4 MB
    u16*  v    = (u16*)(ws + 12587008);              //  4 MB
    u16*  kT   = (u16*)(ws + 16781312);              //  4 MB
    u16*  pO   = (u16*)(ws + 20975616);              // 16 MB partial O
    float* mb  = (float*)(ws + 37752832);            // 256 KB
    float* lb  = (float*)(ws + 38014976);            // 256 KB
    u16*  h2   = (u16*)(ws + 38277120);              //  4 MB
    // total ~40.5 MB

    gn_stats<<<32, 256, 0, stream>>>(x, stats);
    gn_apply<<<2048, 256, 0, stream>>>(x, gn_w, gn_b, stats, h);
    qkv_proj<<<4 * 384 * 16, 256, 0, stream>>>(h, w_qkv, b_qkv, q, k, v);
    ktrans<<<256, 256, 0, stream>>>(k, kT);
    flash_attn<<<512, 256, 0, stream>>>(q, kT, v, pO, mb, lb);
    merge_attn<<<512, 256, 0, stream>>>(pO, mb, lb, h2);
    out_proj<<<4 * 128 * 16, 256, 0, stream>>>(h2, w_out, b_out, x, out);
}

// Round 3
// 185.050 us; speedup vs baseline: 4.9722x; 1.6966x over previous
//
#include <hip/hip_runtime.h>

// AttentionBlock B=4, C=128, N=4096.
// gn_stats -> qkv_fused (GN apply + MFMA QKV proj; qT/kT [n][c], v [c][n])
// -> flash_attn (MFMA 16x16x32 bf16, 4-way j-split, online softmax base-2)
// -> merge_out (merge partials + MFMA out-proj + bias + residual)

#define CH 128
#define SEQ 4096
#define EPSV 1e-5f
// 1/sqrt(128) * log2(e): softmax runs in base-2 domain
#define QSCALE (0.08838834764831845f * 1.4426950408889634f)

typedef unsigned short u16;
typedef unsigned int u32;
typedef __attribute__((ext_vector_type(8))) short short8;   // 8 bf16 (4 VGPRs)
typedef __attribute__((ext_vector_type(4))) float floatx4;  // MFMA C/D

__device__ __forceinline__ float bf2f(u16 h) {
    return __uint_as_float(((u32)h) << 16);
}
__device__ __forceinline__ u16 f2bf(float f) {
    u32 u = __float_as_uint(f);
    return (u16)((u + 0x7fffu + ((u >> 16) & 1u)) >> 16);
}
__device__ __forceinline__ floatx4 mfma16(short8 a, short8 b, floatx4 c) {
    return __builtin_amdgcn_mfma_f32_16x16x32_bf16(a, b, c, 0, 0, 0);
}

// ---------------- Kernel 1: GroupNorm statistics -------------------------------
__global__ void gn_stats(const float* __restrict__ x, float* __restrict__ stats) {
    int bg = blockIdx.x;  // 32
    const float4* xp = (const float4*)(x + (size_t)bg * 65536);
    float s = 0.f, sq = 0.f;
    for (int r = 0; r < 64; ++r) {
        float4 v = xp[threadIdx.x + 256 * r];
        s  += v.x + v.y + v.z + v.w;
        sq += v.x*v.x + v.y*v.y + v.z*v.z + v.w*v.w;
    }
    for (int off = 32; off; off >>= 1) {
        s  += __shfl_down(s, off, 64);
        sq += __shfl_down(sq, off, 64);
    }
    __shared__ float ls[8];
    int wave = threadIdx.x >> 6, lane = threadIdx.x & 63;
    if (lane == 0) { ls[wave*2] = s; ls[wave*2+1] = sq; }
    __syncthreads();
    if (threadIdx.x == 0) {
        float ts = 0.f, tq = 0.f;
        for (int w = 0; w < 4; ++w) { ts += ls[w*2]; tq += ls[w*2+1]; }
        float mean = ts / 65536.f;
        float var  = tq / 65536.f - mean * mean;
        stats[bg]      = mean;
        stats[32 + bg] = rsqrtf(var + EPSV);
    }
}

// ---------------- Kernel 2: fused GN-apply + MFMA QKV projection ---------------
// Block = (b, 64-position chunk). Stage GN'd x transposed in LDS hT[64n][136c];
// each wave owns 6 of 24 output tiles (weights in registers).
// q/k tiles: A=hT,B=W -> C[pos][o] -> qT/kT [n][c].  v: A=W,B=hT -> v [c][n].
__global__ __launch_bounds__(256, 1) void qkv_fused(
        const float* __restrict__ x, const float* __restrict__ gw,
        const float* __restrict__ gb, const float* __restrict__ stats,
        const float* __restrict__ w_qkv, const float* __restrict__ b_qkv,
        u16* __restrict__ qT, u16* __restrict__ kT, u16* __restrict__ v) {
    __shared__ __align__(16) u16 hT[64 * 136];
    int bx = blockIdx.x;            // 256
    int nc = bx & 63, b = bx >> 6;
    int n0 = nc * 64;
    int t = threadIdx.x, w = t >> 6, lane = t & 63;
    int quad = lane >> 4, l15 = lane & 15;

    // weight fragments: wave w owns o-tiles T = w*6 .. w*6+5 (T<8: q, <16: k, else v)
    short8 wf[6][4];
    float bqk[6];
    #pragma unroll
    for (int j = 0; j < 6; ++j) {
        int T = w * 6 + j;
        int orow = T * 16 + l15;
        #pragma unroll
        for (int kt = 0; kt < 4; ++kt) {
            short8 f;
            #pragma unroll
            for (int e = 0; e < 8; ++e)
                ((u16*)&f)[e] = f2bf(w_qkv[orow * 128 + kt * 32 + quad * 8 + e]);
            wf[j][kt] = f;
        }
        bqk[j] = b_qkv[orow];   // valid for q/k tiles (row=o=l15-mapped)
    }

    // stage: read x rows, apply GN, write transposed bf16
    #pragma unroll
    for (int r = 0; r < 8; ++r) {
        int u = r * 256 + t;
        int c = u >> 4, col4 = u & 15;
        int bg = b * 8 + (c >> 4);
        float mean = stats[bg], rstd = stats[32 + bg];
        float wgt = gw[c] * rstd;
        float bs = gb[c] - mean * wgt;
        float4 xv = *(const float4*)(x + ((size_t)(b * 128 + c)) * SEQ + n0 + col4 * 4);
        hT[(col4 * 4 + 0) * 136 + c] = f2bf(fmaf(xv.x, wgt, bs));
        hT[(col4 * 4 + 1) * 136 + c] = f2bf(fmaf(xv.y, wgt, bs));
        hT[(col4 * 4 + 2) * 136 + c] = f2bf(fmaf(xv.z, wgt, bs));
        hT[(col4 * 4 + 3) * 136 + c] = f2bf(fmaf(xv.w, wgt, bs));
    }
    __syncthreads();

    floatx4 acc[6][4];
    #pragma unroll
    for (int j = 0; j < 6; ++j)
        #pragma unroll
        for (int nt = 0; nt < 4; ++nt) acc[j][nt] = (floatx4)0.f;

    bool qk = (w * 6 + 5) < 16;       // wave 0,1 pure-or-mixed handled per-tile below
    #pragma unroll
    for (int nt = 0; nt < 4; ++nt)
        #pragma unroll
        for (int kt = 0; kt < 4; ++kt) {
            short8 hf = *(const short8*)(hT + (nt * 16 + l15) * 136 + kt * 32 + quad * 8);
            #pragma unroll
            for (int j = 0; j < 6; ++j) {
                if (w * 6 + j < 16) acc[j][nt] = mfma16(hf, wf[j][kt], acc[j][nt]);
                else                acc[j][nt] = mfma16(wf[j][kt], hf, acc[j][nt]);
            }
        }
    (void)qk;

    #pragma unroll
    for (int j = 0; j < 6; ++j) {
        int T = w * 6 + j;
        if (T < 8) {            // q: C[pos][o], scale+bias, store qT[n][c]
            int o = T * 16 + l15;
            #pragma unroll
            for (int nt = 0; nt < 4; ++nt)
                #pragma unroll
                for (int r = 0; r < 4; ++r) {
                    int n = n0 + nt * 16 + quad * 4 + r;
                    qT[((size_t)b * SEQ + n) * CH + o] =
                        f2bf((acc[j][nt][r] + bqk[j]) * QSCALE);
                }
        } else if (T < 16) {    // k: C[pos][o] -> kT[n][c]
            int o = (T - 8) * 16 + l15;
            #pragma unroll
            for (int nt = 0; nt < 4; ++nt)
                #pragma unroll
                for (int r = 0; r < 4; ++r) {
                    int n = n0 + nt * 16 + quad * 4 + r;
                    kT[((size_t)b * SEQ + n) * CH + o] = f2bf(acc[j][nt][r] + bqk[j]);
                }
        } else {                // v: C[o][pos] -> v[c][n]
            #pragma unroll
            for (int r = 0; r < 4; ++r) {
                int ov = (T - 16) * 16 + quad * 4 + r;
                float bv = b_qkv[256 + ov];
                #pragma unroll
                for (int nt = 0; nt < 4; ++nt)
                    v[((size_t)(b * CH + ov)) * SEQ + n0 + nt * 16 + l15] =
                        f2bf(acc[j][nt][r] + bv);
            }
        }
    }
}

// ---------------- Kernel 3: MFMA flash attention -------------------------------
__global__ __launch_bounds__(256, 2) void flash_attn(
        const u16* __restrict__ qT, const u16* __restrict__ kT,
        const u16* __restrict__ v, u16* __restrict__ partO,
        float* __restrict__ mbuf, float* __restrict__ lbuf) {
    __shared__ __align__(16) char smem[54784];
    u16* kts = (u16*)smem;                 // [64 j][136 c]   17408 B
    u16* vts = (u16*)(smem + 17408);       // [128 c][72 j]   18432 B
    u16* ps  = (u16*)(smem + 35840);       // [128 i][72 j]   18432 B
    float* als = (float*)(smem + 54272);   // [128 i]           512 B
    u16* qts = (u16*)smem;                 // [128 i][136 c] (init only)

    int bx = blockIdx.x;                   // 512
    int js = bx & 3, iblk = (bx >> 2) & 31, b = bx >> 7;
    int t = threadIdx.x, w = t >> 6, lane = t & 63;
    int quad = lane >> 4, l15 = lane & 15;
    int i0 = iblk * 128, j0 = js * 1024;

    // ---- stage Q tile (already [n][c]), read A-frags (once) ----
    {
        const u16* qb = qT + ((size_t)b * SEQ + i0) * CH;
        for (int r = 0; r < 8; ++r) {
            int u = r * 256 + t;
            int i = u >> 4, c16 = u & 15;
            *(uint4*)(qts + i * 136 + c16 * 8) =
                *(const uint4*)(qb + (size_t)i * CH + c16 * 8);
        }
    }
    __syncthreads();
    short8 qf[2][4];
    #pragma unroll
    for (int mt = 0; mt < 2; ++mt)
        #pragma unroll
        for (int kt = 0; kt < 4; ++kt)
            qf[mt][kt] = *(const short8*)(qts + (w * 32 + mt * 16 + l15) * 136 + kt * 32 + quad * 8);
    __syncthreads();

    float m_run[8], l_run[8];
    #pragma unroll
    for (int r = 0; r < 8; ++r) { m_run[r] = -INFINITY; l_run[r] = 0.f; }
    floatx4 o[8][2];
    #pragma unroll
    for (int mt = 0; mt < 8; ++mt) { o[mt][0] = (floatx4)0.f; o[mt][1] = (floatx4)0.f; }

    const u16* kTb = kT + ((size_t)b * SEQ + j0) * CH;
    const u16* vb  = v  + (size_t)b * CH * SEQ + j0;

    for (int ch = 0; ch < 16; ++ch) {
        int jb = ch * 64;
        __syncthreads();
        for (int r = 0; r < 4; ++r) {
            int u = r * 256 + t;
            int j = u >> 4, c16 = u & 15;
            *(uint4*)(kts + j * 136 + c16 * 8) =
                *(const uint4*)(kTb + (size_t)(jb + j) * CH + c16 * 8);
        }
        for (int r = 0; r < 4; ++r) {
            int u = r * 256 + t;
            int c = u >> 3, col = u & 7;
            *(uint4*)(vts + c * 72 + col * 8) =
                *(const uint4*)(vb + (size_t)c * SEQ + jb + col * 8);
        }
        __syncthreads();

        // ---- scores ----
        floatx4 s[2][4];
        #pragma unroll
        for (int mt = 0; mt < 2; ++mt)
            #pragma unroll
            for (int jt = 0; jt < 4; ++jt) s[mt][jt] = (floatx4)0.f;
        #pragma unroll
        for (int jt = 0; jt < 4; ++jt)
            #pragma unroll
            for (int kt = 0; kt < 4; ++kt) {
                short8 bf = *(const short8*)(kts + (jt * 16 + l15) * 136 + kt * 32 + quad * 8);
                s[0][jt] = mfma16(qf[0][kt], bf, s[0][jt]);
                s[1][jt] = mfma16(qf[1][kt], bf, s[1][jt]);
            }

        // ---- online softmax (base-2), P -> ps (own-wave slab) ----
        #pragma unroll
        for (int mt = 0; mt < 2; ++mt) {
            float al[4];
            #pragma unroll
            for (int r = 0; r < 4; ++r) {
                float mx = fmaxf(fmaxf(s[mt][0][r], s[mt][1][r]),
                                 fmaxf(s[mt][2][r], s[mt][3][r]));
                mx = fmaxf(mx, __shfl_xor(mx, 1, 64));
                mx = fmaxf(mx, __shfl_xor(mx, 2, 64));
                mx = fmaxf(mx, __shfl_xor(mx, 4, 64));
                mx = fmaxf(mx, __shfl_xor(mx, 8, 64));
                float mo = m_run[mt * 4 + r];
                float mn = fmaxf(mo, mx);
                al[r] = exp2f(mo - mn);
                m_run[mt * 4 + r] = mn;
                float p0 = exp2f(s[mt][0][r] - mn);
                float p1 = exp2f(s[mt][1][r] - mn);
                float p2 = exp2f(s[mt][2][r] - mn);
                float p3 = exp2f(s[mt][3][r] - mn);
                int row = w * 32 + mt * 16 + quad * 4 + r;
                ps[row * 72 +  0 + l15] = f2bf(p0);
                ps[row * 72 + 16 + l15] = f2bf(p1);
                ps[row * 72 + 32 + l15] = f2bf(p2);
                ps[row * 72 + 48 + l15] = f2bf(p3);
                float lsum = p0 + p1 + p2 + p3;
                lsum += __shfl_xor(lsum, 1, 64);
                lsum += __shfl_xor(lsum, 2, 64);
                lsum += __shfl_xor(lsum, 4, 64);
                lsum += __shfl_xor(lsum, 8, 64);
                l_run[mt * 4 + r] = l_run[mt * 4 + r] * al[r] + lsum;
            }
            if (l15 == 0) {
                #pragma unroll
                for (int r = 0; r < 4; ++r) als[w * 32 + mt * 16 + quad * 4 + r] = al[r];
            }
        }
        __builtin_amdgcn_wave_barrier();

        // ---- PV: O^T[c][i] += V[c][j] * P^T[j][i] ----
        float a0 = als[w * 32 + l15];
        float a1 = als[w * 32 + 16 + l15];
        #pragma unroll
        for (int mt = 0; mt < 8; ++mt) { o[mt][0] *= a0; o[mt][1] *= a1; }
        #pragma unroll
        for (int kt = 0; kt < 2; ++kt) {
            short8 pf0 = *(const short8*)(ps + (w * 32 + l15) * 72 + kt * 32 + quad * 8);
            short8 pf1 = *(const short8*)(ps + (w * 32 + 16 + l15) * 72 + kt * 32 + quad * 8);
            #pragma unroll
            for (int mt = 0; mt < 8; ++mt) {
                short8 vf = *(const short8*)(vts + (mt * 16 + l15) * 72 + kt * 32 + quad * 8);
                o[mt][0] = mfma16(vf, pf0, o[mt][0]);
                o[mt][1] = mfma16(vf, pf1, o[mt][1]);
            }
        }
    }

    // ---- epilogue: partial O (bf16) [c][i], m, l ----
    int bi = b * 32 + iblk;
    u16* pb = partO + ((size_t)(js * 128 + bi)) * 16384;
    #pragma unroll
    for (int mt = 0; mt < 8; ++mt)
        #pragma unroll
        for (int nt = 0; nt < 2; ++nt)
            #pragma unroll
            for (int r = 0; r < 4; ++r)
                pb[(mt * 16 + quad * 4 + r) * 128 + w * 32 + nt * 16 + l15] = f2bf(o[mt][nt][r]);
    if (l15 == 0) {
        float* mb = mbuf + ((size_t)(js * 128 + bi)) * 128;
        float* lb = lbuf + ((size_t)(js * 128 + bi)) * 128;
        #pragma unroll
        for (int mt = 0; mt < 2; ++mt)
            #pragma unroll
            for (int r = 0; r < 4; ++r) {
                int i = w * 32 + mt * 16 + quad * 4 + r;
                mb[i] = m_run[mt * 4 + r];
                lb[i] = l_run[mt * 4 + r];
            }
    }
}

// ---------------- Kernel 4: merge partials + MFMA out-proj + residual ----------
// Block = (b, iblk, half): 64 positions. fac -> weighted partO sum -> LDS h2T
// -> out = Wout*h2 + bias + x.
__global__ __launch_bounds__(256, 1) void merge_out(
        const u16* __restrict__ partO, const float* __restrict__ mbuf,
        const float* __restrict__ lbuf, const float* __restrict__ w_out,
        const float* __restrict__ b_out, const float* __restrict__ x,
        float* __restrict__ out) {
    __shared__ __align__(16) u16 h2T[64 * 136];   // [i_local][c]
    __shared__ float fac[4][64];
    int bx = blockIdx.x;           // 256
    int half = bx & 1, iblk = (bx >> 1) & 31, b = bx >> 6;
    int bi = b * 32 + iblk;
    int t = threadIdx.x, w = t >> 6, lane = t & 63;
    int quad = lane >> 4, l15 = lane & 15;

    // weight fragments: wave w -> o-tiles 2w, 2w+1
    short8 wf[2][4];
    #pragma unroll
    for (int j = 0; j < 2; ++j)
        #pragma unroll
        for (int kt = 0; kt < 4; ++kt) {
            short8 f;
            #pragma unroll
            for (int e = 0; e < 8; ++e)
                ((u16*)&f)[e] = f2bf(w_out[((w * 2 + j) * 16 + l15) * 128 + kt * 32 + quad * 8 + e]);
            wf[j][kt] = f;
        }

    if (t < 64) {
        int i = half * 64 + t;
        float mv[4], lv[4];
        #pragma unroll
        for (int s = 0; s < 4; ++s) {
            mv[s] = mbuf[((size_t)(s * 128 + bi)) * 128 + i];
            lv[s] = lbuf[((size_t)(s * 128 + bi)) * 128 + i];
        }
        float M = fmaxf(fmaxf(mv[0], mv[1]), fmaxf(mv[2], mv[3]));
        float w0 = exp2f(mv[0] - M), w1 = exp2f(mv[1] - M);
        float w2 = exp2f(mv[2] - M), w3 = exp2f(mv[3] - M);
        float inv = 1.f / (w0 * lv[0] + w1 * lv[1] + w2 * lv[2] + w3 * lv[3]);
        fac[0][t] = w0 * inv; fac[1][t] = w1 * inv;
        fac[2][t] = w2 * inv; fac[3][t] = w3 * inv;
    }
    __syncthreads();

    // merge 4 partials for 32 i each, write transposed bf16 to LDS
    {
        int c = t >> 1, ih = t & 1;
        float accv[32];
        #pragma unroll
        for (int e = 0; e < 32; ++e) accv[e] = 0.f;
        for (int s = 0; s < 4; ++s) {
            const u16* pb = partO + ((size_t)(s * 128 + bi)) * 16384
                            + c * 128 + half * 64 + ih * 32;
            const float* fs = &fac[s][ih * 32];
            #pragma unroll
            for (int e = 0; e < 32; ++e) accv[e] = fmaf(bf2f(pb[e]), fs[e], accv[e]);
        }
        #pragma unroll
        for (int e = 0; e < 32; ++e) h2T[(ih * 32 + e) * 136 + c] = f2bf(accv[e]);
    }
    __syncthreads();

    // out-proj MFMA: A=Wout, B=h2T
    floatx4 acc[2][4];
    #pragma unroll
    for (int j = 0; j < 2; ++j)
        #pragma unroll
        for (int nt = 0; nt < 4; ++nt) acc[j][nt] = (floatx4)0.f;
    #pragma unroll
    for (int nt = 0; nt < 4; ++nt)
        #pragma unroll
        for (int kt = 0; kt < 4; ++kt) {
            short8 hf = *(const short8*)(h2T + (nt * 16 + l15) * 136 + kt * 32 + quad * 8);
            acc[0][nt] = mfma16(wf[0][kt], hf, acc[0][nt]);
            acc[1][nt] = mfma16(wf[1][kt], hf, acc[1][nt]);
        }

    int n_base = iblk * 128 + half * 64;
    #pragma unroll
    for (int j = 0; j < 2; ++j)
        #pragma unroll
        for (int r = 0; r < 4; ++r) {
            int o = w * 32 + j * 16 + quad * 4 + r;
            float bo = b_out[o];
            #pragma unroll
            for (int nt = 0; nt < 4; ++nt) {
                int n = n_base + nt * 16 + l15;
                size_t idx = ((size_t)(b * 128 + o)) * SEQ + n;
                out[idx] = acc[j][nt][r] + bo + x[idx];
            }
        }
}

// ---------------- launch -------------------------------------------------------
extern "C" void kernel_launch(void* const* d_in, const int* in_sizes, int n_in,
                              void* d_out, int out_size, void* d_ws, size_t ws_size,
                              hipStream_t stream) {
    const float* x     = (const float*)d_in[0];
    const float* gn_w  = (const float*)d_in[1];
    const float* gn_b  = (const float*)d_in[2];
    const float* w_qkv = (const float*)d_in[3];
    const float* b_qkv = (const float*)d_in[4];
    const float* w_out = (const float*)d_in[5];
    const float* b_out = (const float*)d_in[6];
    float* out = (float*)d_out;

    char* ws = (char*)d_ws;
    float* stats = (float*)ws;                 //   4 KB @ 0
    u16*  qT  = (u16*)(ws + 4096);             //  4 MB [b][n][c]
    u16*  kT  = (u16*)(ws + 4198400);          //  4 MB [b][n][c]
    u16*  v   = (u16*)(ws + 8392704);          //  4 MB [b][c][n]
    u16*  pO  = (u16*)(ws + 12587008);         // 16 MB partial O [c][i] tiles
    float* mb = (float*)(ws + 29364224);       // 256 KB
    float* lb = (float*)(ws + 29626368);       // 256 KB
    // total ~29.9 MB

    gn_stats<<<32, 256, 0, stream>>>(x, stats);
    qkv_fused<<<256, 256, 0, stream>>>(x, gn_w, gn_b, stats, w_qkv, b_qkv, qT, kT, v);
    flash_attn<<<512, 256, 0, stream>>>(qT, kT, v, pO, mb, lb);
    merge_out<<<256, 256, 0, stream>>>(pO, mb, lb, w_out, b_out, x, out);
}